// Round 5
// baseline (335.114 us; speedup 1.0000x reference)
//
#include <hip/hip_runtime.h>
#include <hip/hip_cooperative_groups.h>

namespace cg = cooperative_groups;

// Problem constants (B=64, C=512, H=W=32 -> HW=1024)
#define B_  64
#define C_  512
#define HW_ 1024
#define NCHUNK 16
#define CPC (C_ / NCHUNK)   // 32 channels per chunk

__device__ __forceinline__ float waveReduceSum(float v) {
    #pragma unroll
    for (int off = 32; off > 0; off >>= 1) v += __shfl_xor(v, off);
    return v;
}

__device__ __forceinline__ float waveReduceMax(float v) {
    #pragma unroll
    for (int off = 32; off > 0; off >>= 1) v = fmaxf(v, __shfl_xor(v, off));
    return v;
}

// ---------------------------------------------------------------------------
// Single cooperative kernel. grid = B*NCHUNK = 1024 blocks (4/CU), 256 thr.
// Block id (after XCD swizzle) = (b, chunk).
// Phase 1: partial dot over its 32 channels, + fold chunk's g.w contribution.
// grid.sync()
// Phase 2: redundant per-block softmax from the 16 partials (L2-local after
// swizzle), then pool its own 32 channels (l re-read; L2/L3-resident).
// ---------------------------------------------------------------------------
__global__ __launch_bounds__(256, 4) void fused_attn(
        const float* __restrict__ l,
        const float* __restrict__ g,
        const float* __restrict__ w,
        float* __restrict__ part,
        float* __restrict__ c_out,
        float* __restrict__ gout) {
    __shared__ float a_lds[HW_];
    __shared__ float red[4];

    // bijective XCD-contiguous swizzle: 1024 wgs, 8 XCDs, 128 ids per XCD.
    // All 16 chunks of a batch land on the same XCD -> partials are L2-local.
    const int wg = blockIdx.x;
    const int id = (wg & 7) * (1024 / 8) + (wg >> 3);
    const int b     = id >> 4;      // / NCHUNK
    const int chunk = id & 15;      // % NCHUNK
    const int tid   = threadIdx.x;
    const int lane  = tid & 63;
    const int wid   = tid >> 6;     // 4 waves

    // ---- Phase 1: partial channel dots (streaming read of l, coalesced) ----
    const float4* l4 = reinterpret_cast<const float4*>(l) +
                       (size_t)id * CPC * (HW_ / 4);
    float4 acc = {0.f, 0.f, 0.f, 0.f};
    float gwc = 0.f;                 // this chunk's share of sum_c g[b,c]*w[c]
    #pragma unroll 8
    for (int i = 0; i < CPC; ++i) {
        const int c = chunk * CPC + i;
        const float wv = w[c];                       // wave-uniform -> scalar
        gwc = fmaf(g[b * C_ + c], wv, gwc);          // wave-uniform -> scalar
        const float4 v = l4[i * (HW_ / 4) + tid];
        acc.x = fmaf(v.x, wv, acc.x);
        acc.y = fmaf(v.y, wv, acc.y);
        acc.z = fmaf(v.z, wv, acc.z);
        acc.w = fmaf(v.w, wv, acc.w);
    }
    // fold the broadcast g.w term into the partial: sum over chunks of gwc
    // reconstructs the full gw[b], so phase 2 needs no gw reduction.
    acc.x += gwc; acc.y += gwc; acc.z += gwc; acc.w += gwc;
    reinterpret_cast<float4*>(part)[(size_t)id * (HW_ / 4) + tid] = acc;

    cg::this_grid().sync();

    // ---- Phase 2a: c values (sum of 16 partials; gw already included) ----
    const float4* part4 = reinterpret_cast<const float4*>(part) +
                          (size_t)b * NCHUNK * (HW_ / 4);
    float4 c4 = {0.f, 0.f, 0.f, 0.f};
    #pragma unroll
    for (int k = 0; k < NCHUNK; ++k) {
        const float4 v = part4[k * (HW_ / 4) + tid];
        c4.x += v.x; c4.y += v.y; c4.z += v.z; c4.w += v.w;
    }

    // ---- Phase 2b: block softmax over 1024 values ----
    float m = fmaxf(fmaxf(c4.x, c4.y), fmaxf(c4.z, c4.w));
    m = waveReduceMax(m);
    if (lane == 0) red[wid] = m;
    __syncthreads();
    m = fmaxf(fmaxf(red[0], red[1]), fmaxf(red[2], red[3]));

    float4 e4;
    e4.x = __expf(c4.x - m);
    e4.y = __expf(c4.y - m);
    e4.z = __expf(c4.z - m);
    e4.w = __expf(c4.w - m);
    float s = e4.x + e4.y + e4.z + e4.w;
    s = waveReduceSum(s);
    __syncthreads();                 // red[] reuse guard
    if (lane == 0) red[wid] = s;
    __syncthreads();
    s = red[0] + red[1] + red[2] + red[3];
    const float inv = __frcp_rn(s);

    float4 a4 = {e4.x * inv, e4.y * inv, e4.z * inv, e4.w * inv};
    reinterpret_cast<float4*>(a_lds)[tid] = a4;
    if (chunk == 0)                  // one block per batch writes the logits
        reinterpret_cast<float4*>(c_out + (size_t)b * HW_)[tid] = c4;
    __syncthreads();

    // ---- Phase 2c: pooling; wave wid owns 8 channels, a-frag in registers --
    float4 av[4];
    #pragma unroll
    for (int i = 0; i < 4; ++i)
        av[i] = reinterpret_cast<float4*>(a_lds)[i * 64 + lane];

    #pragma unroll
    for (int ch = 0; ch < 8; ++ch) {
        const int c = chunk * CPC + wid * 8 + ch;
        const float4* lr = reinterpret_cast<const float4*>(l) +
                           ((size_t)b * C_ + c) * (HW_ / 4);
        float sacc = 0.f;
        #pragma unroll
        for (int i = 0; i < 4; ++i) {
            const float4 v = lr[i * 64 + lane];
            sacc = fmaf(v.x, av[i].x, sacc);
            sacc = fmaf(v.y, av[i].y, sacc);
            sacc = fmaf(v.z, av[i].z, sacc);
            sacc = fmaf(v.w, av[i].w, sacc);
        }
        sacc = waveReduceSum(sacc);
        if (lane == 0) gout[(size_t)b * C_ + c] = sacc;
    }
}

// ---------------------------------------------------------------------------
extern "C" void kernel_launch(void* const* d_in, const int* in_sizes, int n_in,
                              void* d_out, int out_size, void* d_ws, size_t ws_size,
                              hipStream_t stream) {
    const float* l = (const float*)d_in[0];   // [B, C, H, W]
    const float* g = (const float*)d_in[1];   // [B, C]
    const float* w = (const float*)d_in[2];   // [C]
    float* c_out = (float*)d_out;             // c logits: B*HW floats
    float* gout  = (float*)d_out + (size_t)B_ * HW_;  // g_out: B*C floats
    float* part  = (float*)d_ws;              // B*NCHUNK*HW floats = 4 MiB

    void* args[] = {(void*)&l, (void*)&g, (void*)&w,
                    (void*)&part, (void*)&c_out, (void*)&gout};
    (void)hipLaunchCooperativeKernel((const void*)fused_attn,
                                     dim3(B_ * NCHUNK), dim3(256),
                                     args, 0, stream);
}

// Round 6
// 219.642 us; speedup vs baseline: 1.5257x; 1.5257x over previous
//
#include <hip/hip_runtime.h>

// Problem constants (B=64, C=512, H=W=32 -> HW=1024)
#define B_  64
#define C_  512
#define HW_ 1024
#define NCHUNK 32
#define CPC (C_ / NCHUNK)       // 16 channels per chunk
#define NBLK (B_ * NCHUNK)      // 2048 blocks

__device__ __forceinline__ float waveReduceSum(float v) {
    #pragma unroll
    for (int off = 32; off > 0; off >>= 1) v += __shfl_xor(v, off);
    return v;
}

__device__ __forceinline__ float waveReduceMax(float v) {
    #pragma unroll
    for (int off = 32; off > 0; off >>= 1) v = fmaxf(v, __shfl_xor(v, off));
    return v;
}

// bijective XCD-contiguous swizzle for 2048 wgs on 8 XCDs (256 ids/XCD).
// Same mapping in both kernels -> producer XCD == consumer XCD for part/l.
__device__ __forceinline__ int swz(int wg) {
    return (wg & 7) * (NBLK / 8) + (wg >> 3);
}

// ---------------------------------------------------------------------------
// Kernel A: partial channel dot-products (one streaming HBM pass of l).
// 2048 blocks (8/CU), 256 thr. Block id=(b,chunk) covers 16 channels.
// All 16 float4 loads prefetched into registers before the FMA chain ->
// deep load pipeline (fix for the VGPR=32 / 2-loads-in-flight pathology).
// ---------------------------------------------------------------------------
__global__ __launch_bounds__(256) void kA_partial_dot(
        const float* __restrict__ l,
        const float* __restrict__ w,
        float* __restrict__ part) {
    const int id  = swz(blockIdx.x);
    const int tid = threadIdx.x;
    const int c0  = (id & (NCHUNK - 1)) * CPC;   // first channel of chunk

    const float4* l4 = reinterpret_cast<const float4*>(l) +
                       (size_t)id * CPC * (HW_ / 4);

    float4 v[CPC];
    #pragma unroll
    for (int i = 0; i < CPC; ++i) v[i] = l4[i * (HW_ / 4) + tid];

    float4 acc = {0.f, 0.f, 0.f, 0.f};
    #pragma unroll
    for (int i = 0; i < CPC; ++i) {
        const float wv = w[c0 + i];              // block-uniform -> scalar
        acc.x = fmaf(v[i].x, wv, acc.x);
        acc.y = fmaf(v[i].y, wv, acc.y);
        acc.z = fmaf(v[i].z, wv, acc.z);
        acc.w = fmaf(v[i].w, wv, acc.w);
    }
    reinterpret_cast<float4*>(part)[(size_t)id * (HW_ / 4) + tid] = acc;
}

// ---------------------------------------------------------------------------
// Kernel B: fused {gw + partial-reduce + softmax + pooling}.
// 2048 blocks (8/CU), 256 thr = 4 waves. Block id=(b,chunk) redundantly
// computes its batch's softmax from the 32 partial rows (L2-local after the
// swizzle), then pools its own 16 channels (4/wave, parallel accumulators,
// reduces deferred to the end for max loads-in-flight).
// ---------------------------------------------------------------------------
__global__ __launch_bounds__(256) void kB_softmax_pool(
        const float* __restrict__ l,
        const float* __restrict__ part,
        const float* __restrict__ g,
        const float* __restrict__ w,
        float* __restrict__ c_out,
        float* __restrict__ gout) {
    __shared__ float a_lds[HW_];
    __shared__ float red[4];

    const int id    = swz(blockIdx.x);
    const int b     = id >> 5;              // / NCHUNK
    const int chunk = id & (NCHUNK - 1);
    const int tid   = threadIdx.x;
    const int lane  = tid & 63;
    const int wid   = tid >> 6;             // 4 waves

    // --- gw[b] = sum_c g[b,c]*w[c] (each thread covers 2 channels) ---
    float p = g[b * C_ + tid] * w[tid] + g[b * C_ + 256 + tid] * w[256 + tid];
    p = waveReduceSum(p);
    if (lane == 0) red[wid] = p;
    __syncthreads();
    const float gw = red[0] + red[1] + red[2] + red[3];

    // --- c for this thread's 4 hw: gw + sum of 32 partial rows (8-staged) ---
    const float4* part4 = reinterpret_cast<const float4*>(part) +
                          (size_t)b * NCHUNK * (HW_ / 4);
    float4 c4 = {gw, gw, gw, gw};
    #pragma unroll
    for (int kk = 0; kk < NCHUNK / 8; ++kk) {
        float4 v[8];
        #pragma unroll
        for (int i = 0; i < 8; ++i)
            v[i] = part4[(kk * 8 + i) * (HW_ / 4) + tid];
        #pragma unroll
        for (int i = 0; i < 8; ++i) {
            c4.x += v[i].x; c4.y += v[i].y; c4.z += v[i].z; c4.w += v[i].w;
        }
    }

    // --- block max over 1024 values ---
    float m = fmaxf(fmaxf(c4.x, c4.y), fmaxf(c4.z, c4.w));
    m = waveReduceMax(m);
    __syncthreads();                 // red[] reuse guard (gw read above)
    if (lane == 0) red[wid] = m;
    __syncthreads();
    m = fmaxf(fmaxf(red[0], red[1]), fmaxf(red[2], red[3]));

    // --- exp + block sum ---
    float4 e4;
    e4.x = __expf(c4.x - m);
    e4.y = __expf(c4.y - m);
    e4.z = __expf(c4.z - m);
    e4.w = __expf(c4.w - m);
    float s = e4.x + e4.y + e4.z + e4.w;
    s = waveReduceSum(s);
    __syncthreads();                 // red[] reuse guard
    if (lane == 0) red[wid] = s;
    __syncthreads();
    s = red[0] + red[1] + red[2] + red[3];
    const float inv = __frcp_rn(s);

    // --- a -> LDS; chunk 0 writes c logits ---
    float4 a4 = {e4.x * inv, e4.y * inv, e4.z * inv, e4.w * inv};
    reinterpret_cast<float4*>(a_lds)[tid] = a4;
    if (chunk == 0)
        reinterpret_cast<float4*>(c_out + (size_t)b * HW_)[tid] = c4;
    __syncthreads();

    // --- pooling: wave wid owns 4 channels; frag-major independent loads ---
    float4 av[4];
    #pragma unroll
    for (int i = 0; i < 4; ++i)
        av[i] = reinterpret_cast<float4*>(a_lds)[i * 64 + lane];

    const int cbase = chunk * CPC + wid * 4;
    const float4* lr = reinterpret_cast<const float4*>(l) +
                       ((size_t)b * C_ + cbase) * (HW_ / 4);
    float sacc[4] = {0.f, 0.f, 0.f, 0.f};
    #pragma unroll
    for (int i = 0; i < 4; ++i) {            // fragment index
        #pragma unroll
        for (int ch = 0; ch < 4; ++ch) {     // 4 independent channel rows
            const float4 v = lr[ch * (HW_ / 4) + i * 64 + lane];
            sacc[ch] = fmaf(v.x, av[i].x, sacc[ch]);
            sacc[ch] = fmaf(v.y, av[i].y, sacc[ch]);
            sacc[ch] = fmaf(v.z, av[i].z, sacc[ch]);
            sacc[ch] = fmaf(v.w, av[i].w, sacc[ch]);
        }
    }
    #pragma unroll
    for (int ch = 0; ch < 4; ++ch) {
        const float r = waveReduceSum(sacc[ch]);
        if (lane == 0) gout[(size_t)b * C_ + cbase + ch] = r;
    }
}

// ---------------------------------------------------------------------------
extern "C" void kernel_launch(void* const* d_in, const int* in_sizes, int n_in,
                              void* d_out, int out_size, void* d_ws, size_t ws_size,
                              hipStream_t stream) {
    const float* l = (const float*)d_in[0];   // [B, C, H, W]
    const float* g = (const float*)d_in[1];   // [B, C]
    const float* w = (const float*)d_in[2];   // [C]
    float* c_out = (float*)d_out;                     // c: B*HW floats
    float* gout  = (float*)d_out + (size_t)B_ * HW_;  // g_out: B*C floats
    float* part  = (float*)d_ws;                      // NBLK*HW floats = 8 MiB

    kA_partial_dot<<<NBLK, 256, 0, stream>>>(l, w, part);
    kB_softmax_pool<<<NBLK, 256, 0, stream>>>(l, part, g, w, c_out, gout);
}

// Round 7
// 202.653 us; speedup vs baseline: 1.6536x; 1.0838x over previous
//
#include <hip/hip_runtime.h>

// Problem constants (B=64, C=512, H=W=32 -> HW=1024)
#define B_    64
#define C_    512
#define HW_   1024
#define S_    32                 // hw positions per slab
#define NSLAB (HW_ / S_)         // 32 slabs per batch
#define TPB   512                // 8 waves
#define NGRP  (TPB / S_)         // 16 channel groups in c-phase
#define CPG   (C_ / NGRP)        // 32 channels per group
#define TSTR  (S_ + 1)           // padded LDS row stride (33 floats)

// ---------------------------------------------------------------------------
// Kernel 1: slab-local {conv + online-softmax stats + weighted pooling part}.
// grid = B*NSLAB = 2048 blocks, 512 thr (2 blocks/CU: 69.9 KB LDS each).
// Reads l exactly ONCE from HBM (the only big pass in the whole op):
//   stage slab l[b,:,hw0:hw0+32] (64 KB) -> LDS, then
//   c[hw]   = sum_ch l*w + g.w          (exact, wave0 finalizes)
//   m_s,E_s = max / sum e^{c-m_s}       (32-lane softmax stats)
//   U_s[ch] = sum_hw l[ch,hw]*e^{c[hw]-m_s}   (from LDS, no global re-read)
// ---------------------------------------------------------------------------
__global__ __launch_bounds__(TPB) void k1_slab(
        const float* __restrict__ l,
        const float* __restrict__ g,
        const float* __restrict__ w,
        float* __restrict__ c_out,
        float* __restrict__ U,
        float2* __restrict__ stats) {
    __shared__ float tile[C_ * TSTR];        // 67,584 B, padded rows
    __shared__ float e_lds[S_];
    __shared__ float red[S_ * (NGRP + 1)];   // [32][17] padded
    __shared__ float red2[TPB / 64];         // gw wave partials

    const int blk  = blockIdx.x;
    const int b    = blk >> 5;               // / NSLAB
    const int slab = blk & (NSLAB - 1);
    const int t    = threadIdx.x;
    const int lane = t & 63;
    const int wid  = t >> 6;

    // --- gw partial: thread t covers channel t (512 == TPB) ---
    float p = g[b * C_ + t] * w[t];
    #pragma unroll
    for (int off = 32; off > 0; off >>= 1) p += __shfl_xor(p, off);
    if (lane == 0) red2[wid] = p;

    // --- stage slab into LDS: 8 float4 per thread, deep in flight ---
    const float4* l4 = reinterpret_cast<const float4*>(l);
    float4 v[8];
    #pragma unroll
    for (int i = 0; i < 8; ++i) {
        const int k  = i * TPB + t;
        const int ch = k >> 3, j = k & 7;    // 8 float4 per channel row
        v[i] = l4[((size_t)b * C_ + ch) * (HW_ / 4) + slab * (S_ / 4) + j];
    }
    #pragma unroll
    for (int i = 0; i < 8; ++i) {
        const int k  = i * TPB + t;
        const int ch = k >> 3, j = k & 7;
        float* dst = &tile[ch * TSTR + 4 * j];
        dst[0] = v[i].x; dst[1] = v[i].y; dst[2] = v[i].z; dst[3] = v[i].w;
    }
    __syncthreads();

    // --- c-phase: thread (hw = t&31, grp = t>>5) sums its 32 channels ---
    const int hw  = t & (S_ - 1);
    const int grp = t >> 5;
    float acc = 0.f;
    #pragma unroll 8
    for (int i = 0; i < CPG; ++i) {
        const int ch = grp * CPG + i;
        acc = fmaf(tile[ch * TSTR + hw], w[ch], acc);
    }
    red[hw * (NGRP + 1) + grp] = acc;
    __syncthreads();

    // --- wave0 lanes 0-31: finalize c, softmax stats, e -> LDS ---
    if (t < S_) {
        float c = 0.f;
        #pragma unroll
        for (int gp = 0; gp < NGRP; ++gp) c += red[t * (NGRP + 1) + gp];
        float gw = 0.f;
        #pragma unroll
        for (int i = 0; i < TPB / 64; ++i) gw += red2[i];
        c += gw;
        c_out[(size_t)b * HW_ + slab * S_ + t] = c;

        float m = c;
        #pragma unroll
        for (int off = 16; off > 0; off >>= 1) m = fmaxf(m, __shfl_xor(m, off));
        const float e = __expf(c - m);
        float E = e;
        #pragma unroll
        for (int off = 16; off > 0; off >>= 1) E += __shfl_xor(E, off);
        e_lds[t] = e;
        if (t == 0) stats[b * NSLAB + slab] = make_float2(m, E);
    }
    __syncthreads();

    // --- U-phase: thread t owns channel t; row read 2-way (free), e bcast ---
    float ua = 0.f;
    #pragma unroll 8
    for (int h = 0; h < S_; ++h)
        ua = fmaf(tile[t * TSTR + h], e_lds[h], ua);
    U[((size_t)b * NSLAB + slab) * C_ + t] = ua;
}

// ---------------------------------------------------------------------------
// Kernel 2: combine slabs. grid = B blocks, 256 thr. Reads U (4 MB, L2/L3).
// g_out[b,ch] = sum_s U_s[ch] * e^{m_s - m} / Z,  Z = sum_s E_s * e^{m_s - m}.
// ---------------------------------------------------------------------------
__global__ __launch_bounds__(256) void k2_finish(
        const float* __restrict__ U,
        const float2* __restrict__ stats,
        float* __restrict__ gout) {
    __shared__ float scale_lds[NSLAB];
    __shared__ float invZ_lds;
    const int b = blockIdx.x;
    const int t = threadIdx.x;

    if (t < NSLAB) {                         // lanes 0-31 of wave 0
        const float2 me = stats[b * NSLAB + t];
        float m = me.x;
        #pragma unroll
        for (int off = 16; off > 0; off >>= 1) m = fmaxf(m, __shfl_xor(m, off));
        const float sc = __expf(me.x - m);
        float Z = me.y * sc;
        #pragma unroll
        for (int off = 16; off > 0; off >>= 1) Z += __shfl_xor(Z, off);
        scale_lds[t] = sc;
        if (t == 0) invZ_lds = __frcp_rn(Z);
    }
    __syncthreads();
    const float invZ = invZ_lds;

    #pragma unroll
    for (int cc = 0; cc < C_ / 256; ++cc) {
        const int ch = cc * 256 + t;
        float acc = 0.f;
        #pragma unroll 8
        for (int s = 0; s < NSLAB; ++s)
            acc = fmaf(U[((size_t)b * NSLAB + s) * C_ + ch], scale_lds[s], acc);
        gout[(size_t)b * C_ + ch] = acc * invZ;
    }
}

// ---------------------------------------------------------------------------
extern "C" void kernel_launch(void* const* d_in, const int* in_sizes, int n_in,
                              void* d_out, int out_size, void* d_ws, size_t ws_size,
                              hipStream_t stream) {
    const float* l = (const float*)d_in[0];   // [B, C, H, W]
    const float* g = (const float*)d_in[1];   // [B, C]
    const float* w = (const float*)d_in[2];   // [C]
    float*  c_out = (float*)d_out;                      // c: B*HW floats
    float*  gout  = (float*)d_out + (size_t)B_ * HW_;   // g_out: B*C floats
    float*  U     = (float*)d_ws;                       // B*NSLAB*C = 4 MiB
    float2* stats = (float2*)(U + (size_t)B_ * NSLAB * C_);  // B*NSLAB float2

    k1_slab<<<B_ * NSLAB, TPB, 0, stream>>>(l, g, w, c_out, U, stats);
    k2_finish<<<B_, 256, 0, stream>>>(U, stats, gout);
}

// Round 8
// 197.560 us; speedup vs baseline: 1.6963x; 1.0258x over previous
//
#include <hip/hip_runtime.h>

// Problem constants (B=64, C=512, H=W=32 -> HW=1024)
#define B_    64
#define C_    512
#define HW_   1024
#define S_    32                 // hw positions per slab
#define NSLAB (HW_ / S_)         // 32 slabs per batch
#define TPB   512                // 8 waves

// ---------------------------------------------------------------------------
// Kernel 1: register-resident slab {conv + softmax stats + weighted pooling}.
// grid = B*NSLAB = 2048 blocks, 512 thr. No LDS tile: thread t holds hw-quad
// j = t&7 (4 hw values) for the 8 channels {i*64 + (t>>3)} as float4 v[8].
//   c:  per-thread FMA on v[] + shfl_xor(8/16/32) reduce over channel groups
//   stats: 32 lanes finalize c, m_s, E_s, e[32]
//   U:  dot(v[i], e4[j]) + shfl_xor(1/2/4) reduce -> one store per thread
// l is read from HBM exactly once, into registers, and used twice.
// ---------------------------------------------------------------------------
__global__ __launch_bounds__(TPB) void k1_slab(
        const float* __restrict__ l,
        const float* __restrict__ g,
        const float* __restrict__ w,
        float* __restrict__ c_out,
        float* __restrict__ U,
        float2* __restrict__ stats) {
    __shared__ float w_lds[C_];
    __shared__ float redc[8 * 8 * 4];    // [wave][j] float4 c-partials (1 KB)
    __shared__ float redg[8];            // gw wave partials
    __shared__ float e_lds[S_];

    const int blk  = blockIdx.x;
    const int b    = blk >> 5;           // / NSLAB
    const int slab = blk & (NSLAB - 1);
    const int t    = threadIdx.x;
    const int lane = t & 63;
    const int wid  = t >> 6;             // 8 waves
    const int j    = t & 7;              // hw-quad index (hw = 4j..4j+3)
    const int co   = t >> 3;             // channel offset 0..63

    // --- 1. issue all 8 global float4 loads first (deep in flight) ---
    const float4* l4 = reinterpret_cast<const float4*>(l);
    float4 v[8];
    #pragma unroll
    for (int i = 0; i < 8; ++i)
        v[i] = l4[((size_t)b * C_ + (i * 64 + co)) * (HW_ / 4)
                  + slab * (S_ / 4) + j];

    // --- 2. stage w; gw partial (overlaps the loads) ---
    w_lds[t] = w[t];
    float p = g[b * C_ + t] * w[t];
    #pragma unroll
    for (int off = 32; off > 0; off >>= 1) p += __shfl_xor(p, off);
    if (lane == 0) redg[wid] = p;
    __syncthreads();

    // --- 3. c partials: 8 channels x this thread's 4 hw ---
    float4 cp = {0.f, 0.f, 0.f, 0.f};
    #pragma unroll
    for (int i = 0; i < 8; ++i) {
        const float wv = w_lds[i * 64 + co];   // 8-lane same-addr broadcast
        cp.x = fmaf(v[i].x, wv, cp.x);
        cp.y = fmaf(v[i].y, wv, cp.y);
        cp.z = fmaf(v[i].z, wv, cp.z);
        cp.w = fmaf(v[i].w, wv, cp.w);
    }
    // reduce over lane bits 3,4,5 (all lanes sharing this j in the wave)
    #pragma unroll
    for (int m = 8; m <= 32; m <<= 1) {
        cp.x += __shfl_xor(cp.x, m);
        cp.y += __shfl_xor(cp.y, m);
        cp.z += __shfl_xor(cp.z, m);
        cp.w += __shfl_xor(cp.w, m);
    }
    if (lane < 8)                          // lane == j here
        reinterpret_cast<float4*>(redc)[wid * 8 + lane] = cp;
    __syncthreads();

    // --- 4. stats: lanes 0-31 finalize c (hw = t), softmax stats ---
    if (t < S_) {
        float c = 0.f;
        #pragma unroll
        for (int wv = 0; wv < 8; ++wv) c += redc[wv * 32 + t];
        float gw = 0.f;
        #pragma unroll
        for (int i = 0; i < 8; ++i) gw += redg[i];
        c += gw;
        c_out[(size_t)b * HW_ + slab * S_ + t] = c;

        float m = c;
        #pragma unroll
        for (int off = 16; off > 0; off >>= 1) m = fmaxf(m, __shfl_xor(m, off));
        const float e = __expf(c - m);
        float E = e;
        #pragma unroll
        for (int off = 16; off > 0; off >>= 1) E += __shfl_xor(E, off);
        e_lds[t] = e;
        if (t == 0) stats[b * NSLAB + slab] = make_float2(m, E);
    }
    __syncthreads();

    // --- 5. U phase: reuse v[] registers; e4 broadcast per j-group ---
    const float4 e4 = reinterpret_cast<const float4*>(e_lds)[j];
    float u[8];
    #pragma unroll
    for (int i = 0; i < 8; ++i)
        u[i] = v[i].x * e4.x + v[i].y * e4.y + v[i].z * e4.z + v[i].w * e4.w;
    // reduce over lane bits 0,1,2 (the 8 lanes sharing channel i*64+co)
    #pragma unroll
    for (int i = 0; i < 8; ++i) {
        u[i] += __shfl_xor(u[i], 1);
        u[i] += __shfl_xor(u[i], 2);
        u[i] += __shfl_xor(u[i], 4);
    }
    // thread stores the channel whose i equals its j (static-index select)
    float uval = u[0];
    #pragma unroll
    for (int i = 1; i < 8; ++i) if (j == i) uval = u[i];
    U[((size_t)b * NSLAB + slab) * C_ + (j * 64 + co)] = uval;
}

// ---------------------------------------------------------------------------
// Kernel 2: combine slabs. grid = B*8 = 512 blocks, 256 thr = 4 waves.
// Block (b, cg) handles 64 channels; each wave sums 8 slabs; LDS reduce.
// g_out[b,ch] = sum_s U_s[ch] * e^{m_s - m} / Z.
// ---------------------------------------------------------------------------
__global__ __launch_bounds__(256) void k2_finish(
        const float* __restrict__ U,
        const float2* __restrict__ stats,
        float* __restrict__ gout) {
    __shared__ float scale_lds[NSLAB];
    __shared__ float invZ_lds;
    __shared__ float part2[4 * 64];

    const int blk = blockIdx.x;
    const int b   = blk >> 3;
    const int cg  = blk & 7;
    const int t   = threadIdx.x;
    const int wid = t >> 6;
    const int cl  = t & 63;

    if (t < NSLAB) {                       // lanes 0-31 of wave 0
        const float2 me = stats[b * NSLAB + t];
        float m = me.x;
        #pragma unroll
        for (int off = 16; off > 0; off >>= 1) m = fmaxf(m, __shfl_xor(m, off));
        const float sc = __expf(me.x - m);
        float Z = me.y * sc;
        #pragma unroll
        for (int off = 16; off > 0; off >>= 1) Z += __shfl_xor(Z, off);
        scale_lds[t] = sc;
        if (t == 0) invZ_lds = __frcp_rn(Z);
    }
    __syncthreads();

    const int ch = cg * 64 + cl;
    float acc = 0.f;
    #pragma unroll
    for (int si = 0; si < 8; ++si) {
        const int s = wid * 8 + si;        // wave-uniform -> scale broadcast
        acc = fmaf(U[((size_t)b * NSLAB + s) * C_ + ch], scale_lds[s], acc);
    }
    part2[wid * 64 + cl] = acc;
    __syncthreads();

    if (wid == 0) {
        float r = part2[cl] + part2[64 + cl] + part2[128 + cl] + part2[192 + cl];
        gout[(size_t)b * C_ + ch] = r * invZ_lds;
    }
}

// ---------------------------------------------------------------------------
extern "C" void kernel_launch(void* const* d_in, const int* in_sizes, int n_in,
                              void* d_out, int out_size, void* d_ws, size_t ws_size,
                              hipStream_t stream) {
    const float* l = (const float*)d_in[0];   // [B, C, H, W]
    const float* g = (const float*)d_in[1];   // [B, C]
    const float* w = (const float*)d_in[2];   // [C]
    float*  c_out = (float*)d_out;                      // c: B*HW floats
    float*  gout  = (float*)d_out + (size_t)B_ * HW_;   // g_out: B*C floats
    float*  U     = (float*)d_ws;                       // B*NSLAB*C = 4 MiB
    float2* stats = (float2*)(U + (size_t)B_ * NSLAB * C_);  // B*NSLAB float2

    k1_slab<<<B_ * NSLAB, TPB, 0, stream>>>(l, g, w, c_out, U, stats);
    k2_finish<<<B_ * 8, 256, 0, stream>>>(U, stats, gout);
}